// Round 13
// baseline (23.938 us; speedup 1.0000x reference)
//
#include <hip/hip_runtime.h>
#include <math.h>

// HungarianMatcher cost matrix:
//   C[i,j] = 5*L1(pred_box_i, tgt_box_j) + 2*focal(tgt class j) - 2*GIoU
// Shapes: pred_logits [BN,NC], pred_boxes [BN,4], tgt_ids [NT], tgt_bbox [NT,4]
// BN=16*900=14400, NC=91, NT=960. Output [BN,NT] fp32.
//
// R12: ROWS=1 (grid 14400). Block-granularity is the only lever that has
// moved the 24->21us plateau (ROWS 8/4/2 = 24.8/23.8/21.0): latency-bound,
// more independent blocks = better hiding. Per-block: 91-entry focal table
// (1 chain for 91/256 threads), branchless body-before-barrier (R11),
// single barrier, 1 NT float4 store per thread. tboxes/tids are L1-resident
// across a CU's consecutive blocks; logits read exactly once chip-wide.

#define ALPHA_F   0.25f
#define COST_CLS  2.0f
#define COST_BBOX 5.0f
#define COST_GIOU 2.0f
#define EPS_F     1e-8f

constexpr int THREADS = 256;

typedef float vfloat4 __attribute__((ext_vector_type(4)));

__device__ __forceinline__ float focal_entry(float x) {
    const float p  = 1.0f / (1.0f + __expf(-x));
    const float om = 1.0f - p;
    const float neg = (1.0f - ALPHA_F) * p * p * (-__logf(om + EPS_F));
    const float pos = ALPHA_F * om * om        * (-__logf(p  + EPS_F));
    return COST_CLS * (pos - neg) + COST_GIOU;   // GIoU "+2" folded in
}

// ---------------------- specialized kernel (ROWS = 1) -----------------------
template<int NC, int NT>
__global__ __launch_bounds__(THREADS) void matcher_kernel_s(
    const float* __restrict__ logits,   // [BN, NC]
    const float* __restrict__ boxes,    // [BN, 4] cxcywh
    const int*   __restrict__ tids,     // [NT]
    const float* __restrict__ tboxes,   // [NT, 4] cxcywh
    float*       __restrict__ out)      // [BN, NT]
{
    constexpr int JPT = 4;                    // contiguous targets per thread
    constexpr int NJT = NT / JPT;             // 240 active threads

    __shared__ float s_cls[NC];               // 364 B class-major table

    const int tid = threadIdx.x;
    const int row = blockIdx.x;

    // ---- clamped indices: every thread does full work, no divergent BBs ----
    const int jb = (tid < NJT) ? tid : (NJT - 1);
    const int tt = (tid < NC)  ? tid : (NC - 1);

    // ---- issue all loads up front ----
    const float x = logits[(size_t)row * NC + tt];           // cold (HBM)
    const int4 tv = reinterpret_cast<const int4*>(tids)[jb]; // L1 hot
    float4 tb[JPT];
    #pragma unroll
    for (int k = 0; k < JPT; ++k)
        tb[k] = reinterpret_cast<const float4*>(tboxes)[jb * JPT + k];
    const float4 pb = reinterpret_cast<const float4*>(boxes)[row];  // scalar

    // ---- FP body, pure VALU, runs while logit load / trans chain fly ----
    const float px0 = pb.x - 0.5f * pb.z, py0 = pb.y - 0.5f * pb.w;
    const float px1 = pb.x + 0.5f * pb.z, py1 = pb.y + 0.5f * pb.w;
    const float parea = pb.z * pb.w;

    float rv[JPT];
    #pragma unroll
    for (int k = 0; k < JPT; ++k) {
        const float4 t = tb[k];
        const float hw = 0.5f * t.z, hh = 0.5f * t.w;
        const float tx0 = t.x - hw, tx1 = t.x + hw;
        const float ty0 = t.y - hh, ty1 = t.y + hh;
        const float tarea = t.z * t.w;
        // L1 in cxcywh space (abs folds into VOP3 src modifiers)
        const float l1 = (fabsf(pb.x - t.x) + fabsf(pb.y - t.y))
                       + (fabsf(pb.z - t.z) + fabsf(pb.w - t.w));
        // raw intersection extents (feed enclosing box too)
        const float iwr = fminf(px1, tx1) - fmaxf(px0, tx0);
        const float ihr = fminf(py1, ty1) - fmaxf(py0, ty0);
        const float inter = fmaxf(iwr, 0.0f) * fmaxf(ihr, 0.0f);
        const float uni = (parea + tarea) - inter;
        // enclosing box via identity: cw = pw + tw - iwr
        const float cw = (pb.z + t.z) - iwr;
        const float ch = (pb.w + t.w) - ihr;
        const float carea = cw * ch;
        // partial C (class cost added post-barrier):
        //   5*l1 - 2*(inter*carea + uni^2)/(uni*carea)
        const float num  = fmaf(inter, carea, uni * uni);
        const float rcpd = __builtin_amdgcn_rcpf(uni * carea);
        rv[k] = fmaf(-2.0f * num, rcpd, COST_BBOX * l1);
    }

    // ---- focal chain (scheduler interleaves into the body above) ----
    const float fe = focal_entry(x);
    if (tid < NC) s_cls[tt] = fe;
    __syncthreads();   // the only barrier; body already done

    if (tid >= NJT) return;

    // ---- tiny tail: 4 LDS gathers + 4 adds + 1 NT store ----
    const int ic[JPT] = {tv.x, tv.y, tv.z, tv.w};
    vfloat4 v;
    v.x = rv[0] + s_cls[ic[0]];
    v.y = rv[1] + s_cls[ic[1]];
    v.z = rv[2] + s_cls[ic[2]];
    v.w = rv[3] + s_cls[ic[3]];
    float* __restrict__ optr = out + (size_t)row * NT + tid * JPT;
    __builtin_nontemporal_store(v, reinterpret_cast<vfloat4*>(optr));
}

// ----------------------------- generic fallback -----------------------------
constexpr int GROWS = 8;
__global__ __launch_bounds__(THREADS) void matcher_kernel_g(
    const float* __restrict__ logits, const float* __restrict__ boxes,
    const int* __restrict__ tids, const float* __restrict__ tboxes,
    float* __restrict__ out, int BN, int NC, int NT)
{
    extern __shared__ float s_cls_g[];
    const int tid  = threadIdx.x;
    const int row0 = blockIdx.x * GROWS;
    const int nrows = (BN - row0 < GROWS) ? (BN - row0) : GROWS;

    for (int t = tid; t < nrows * NC; t += THREADS) {
        const int r = t / NC, c = t - r * NC;
        const float x = logits[(size_t)(row0 + r) * NC + c];
        const float p  = 1.0f / (1.0f + expf(-x));
        const float om = 1.0f - p;
        const float neg = (1.0f - ALPHA_F) * p * p * (-logf(om + EPS_F));
        const float pos = ALPHA_F * om * om        * (-logf(p + EPS_F));
        s_cls_g[r * NC + c] = pos - neg;
    }
    __syncthreads();

    for (int r = 0; r < nrows; ++r) {
        const int row = row0 + r;
        const float4 pb = reinterpret_cast<const float4*>(boxes)[row];
        const float px0 = pb.x - 0.5f * pb.z, py0 = pb.y - 0.5f * pb.w;
        const float px1 = pb.x + 0.5f * pb.z, py1 = pb.y + 0.5f * pb.w;
        const float parea = pb.z * pb.w;
        for (int j = tid; j < NT; j += THREADS) {
            const float4 b = reinterpret_cast<const float4*>(tboxes)[j];
            const float bx0 = b.x - 0.5f * b.z, by0 = b.y - 0.5f * b.w;
            const float bx1 = b.x + 0.5f * b.z, by1 = b.y + 0.5f * b.w;
            const float l1 = fabsf(pb.x - b.x) + fabsf(pb.y - b.y)
                           + fabsf(pb.z - b.z) + fabsf(pb.w - b.w);
            const float iw = fmaxf(fminf(px1, bx1) - fmaxf(px0, bx0), 0.0f);
            const float ih = fmaxf(fminf(py1, by1) - fmaxf(py0, by0), 0.0f);
            const float inter = iw * ih;
            const float uni = parea + b.z * b.w - inter;
            const float iou = inter / uni;
            const float cw = fmaxf(px1, bx1) - fminf(px0, bx0);
            const float ch = fmaxf(py1, by1) - fminf(py0, by0);
            const float carea = cw * ch;
            const float giou = iou - (carea - uni) / carea;
            const float ccls = s_cls_g[r * NC + tids[j]];
            out[(size_t)row * NT + j] = COST_BBOX * l1 + COST_CLS * ccls - COST_GIOU * giou;
        }
        __syncthreads();
    }
}

extern "C" void kernel_launch(void* const* d_in, const int* in_sizes, int n_in,
                              void* d_out, int out_size, void* d_ws, size_t ws_size,
                              hipStream_t stream) {
    const float* logits = (const float*)d_in[0];
    const float* boxes  = (const float*)d_in[1];
    const int*   tids   = (const int*)d_in[2];
    const float* tboxes = (const float*)d_in[3];
    float* out = (float*)d_out;

    const int BN = in_sizes[1] / 4;       // 14400
    const int NC = in_sizes[0] / BN;      // 91
    const int NT = in_sizes[2];           // 960

    if (NC == 91 && NT == 960) {
        matcher_kernel_s<91, 960><<<BN, THREADS, 0, stream>>>(
            logits, boxes, tids, tboxes, out);
    } else {
        const int grid = (BN + GROWS - 1) / GROWS;
        const size_t shmem = (size_t)GROWS * NC * sizeof(float);
        matcher_kernel_g<<<grid, THREADS, shmem, stream>>>(
            logits, boxes, tids, tboxes, out, BN, NC, NT);
    }
}

// Round 14
// 20.822 us; speedup vs baseline: 1.1496x; 1.1496x over previous
//
#include <hip/hip_runtime.h>
#include <math.h>

// HungarianMatcher cost matrix:
//   C[i,j] = 5*L1(pred_box_i, tgt_box_j) + 2*focal(tgt class j) - 2*GIoU
// Shapes: pred_logits [BN,NC], pred_boxes [BN,4], tgt_ids [NT], tgt_bbox [NT,4]
// BN=16*900=14400, NC=91, NT=960. Output [BN,NT] fp32.
//
// R13: R9b (best, 21us; ROWS=2, grid 7200) with STRIDED target ownership:
// thread tid owns targets {tid, tid+240, tid+480, tid+720}. Every global
// access is now lane-coalesced: tbox float4 loads (16 lines/wave-instr vs 64
// for the old contiguous-JPT layout), tid dword loads (4 lines), and NT dword
// stores (256B contiguous per wave-instr). Theory: the old 64B-lane-stride
// loads serialized L1 (~64 lines per wave-load) and were the hidden ~15us.

#define ALPHA_F   0.25f
#define COST_CLS  2.0f
#define COST_BBOX 5.0f
#define COST_GIOU 2.0f
#define EPS_F     1e-8f

constexpr int THREADS = 256;

__device__ __forceinline__ float focal_entry(float x) {
    const float p  = 1.0f / (1.0f + __expf(-x));
    const float om = 1.0f - p;
    const float neg = (1.0f - ALPHA_F) * p * p * (-__logf(om + EPS_F));
    const float pos = ALPHA_F * om * om        * (-__logf(p  + EPS_F));
    return COST_CLS * (pos - neg) + COST_GIOU;   // GIoU "+2" folded in
}

// ---------------------- specialized kernel (ROWS = 2) -----------------------
template<int NC, int NT>
__global__ __launch_bounds__(THREADS) void matcher_kernel_s(
    const float* __restrict__ logits,   // [BN, NC]
    const float* __restrict__ boxes,    // [BN, 4] cxcywh
    const int*   __restrict__ tids,     // [NT]
    const float* __restrict__ tboxes,   // [NT, 4] cxcywh
    float*       __restrict__ out)      // [BN, NT]
{
    constexpr int ROWS = 2;
    constexpr int JPT  = 4;                   // targets per thread (strided)
    constexpr int NJT  = NT / JPT;            // 240 active threads
    constexpr int NTAB = ROWS * NC;           // 182 table entries
    constexpr int CSTR = 3;                   // class stride (coprime with 32)

    __shared__ float s_cls[NC * CSTR];        // ~1.1 KB

    const int tid  = threadIdx.x;
    const int row0 = blockIdx.x * ROWS;
    const bool active = tid < NJT;

    // ---- issue the logit load first (head of the transcendental chain) ----
    float x = 0.0f;
    if (tid < NTAB)
        x = logits[(size_t)row0 * NC + tid];

    // ---- strided targets: ALL loads lane-coalesced ----
    float4 tb[JPT];
    int ic[JPT] = {0, 0, 0, 0};
    if (active) {
        #pragma unroll
        for (int k = 0; k < JPT; ++k) {
            tb[k] = reinterpret_cast<const float4*>(tboxes)[tid + k * NJT];
            ic[k] = tids[tid + k * NJT];
        }
    } else {
        #pragma unroll
        for (int k = 0; k < JPT; ++k) tb[k] = make_float4(0.f, 0.f, 0.f, 0.f);
    }

    // ---- focal class table: s_cls[c*3 + r], one chain per thread ----
    if (tid < NTAB) {
        const int r = (tid >= NC) ? 1 : 0;
        const int c = tid - (r ? NC : 0);
        s_cls[c * CSTR + r] = focal_entry(x);
    }
    __syncthreads();   // the only barrier

    if (!active) return;

    // ---- prefetch both rows' class costs to registers (8x ds_read_b32) ----
    float cc0[JPT], cc1[JPT];
    #pragma unroll
    for (int k = 0; k < JPT; ++k) {
        const float* cp = s_cls + ic[k] * CSTR;
        cc0[k] = cp[0];
        cc1[k] = cp[1];
    }

    float* __restrict__ obase = out + (size_t)row0 * NT + tid;
    #pragma unroll
    for (int r = 0; r < ROWS; ++r) {
        // block-uniform pred box (scalar-load path)
        const float4 pb = reinterpret_cast<const float4*>(boxes)[row0 + r];
        const float px0 = pb.x - 0.5f * pb.z, py0 = pb.y - 0.5f * pb.w;
        const float px1 = pb.x + 0.5f * pb.z, py1 = pb.y + 0.5f * pb.w;
        const float parea = pb.z * pb.w;

        #pragma unroll
        for (int k = 0; k < JPT; ++k) {
            const float4 t = tb[k];
            const float hw = 0.5f * t.z, hh = 0.5f * t.w;
            const float tx0 = t.x - hw, tx1 = t.x + hw;
            const float ty0 = t.y - hh, ty1 = t.y + hh;
            const float tarea = t.z * t.w;
            // L1 in cxcywh space (abs folds into VOP3 src modifiers)
            const float l1 = (fabsf(pb.x - t.x) + fabsf(pb.y - t.y))
                           + (fabsf(pb.z - t.z) + fabsf(pb.w - t.w));
            // raw intersection extents (feed enclosing box too)
            const float iwr = fminf(px1, tx1) - fmaxf(px0, tx0);
            const float ihr = fminf(py1, ty1) - fmaxf(py0, ty0);
            const float inter = fmaxf(iwr, 0.0f) * fmaxf(ihr, 0.0f);
            const float uni = (parea + tarea) - inter;
            // enclosing box via identity: cw = pw + tw - iwr
            const float cw = (pb.z + t.z) - iwr;
            const float ch = (pb.w + t.w) - ihr;
            const float carea = cw * ch;
            // C = 5*l1 + tbl[c] - 2*(inter*carea + uni^2)/(uni*carea)
            const float num  = fmaf(inter, carea, uni * uni);
            const float rcpd = __builtin_amdgcn_rcpf(uni * carea);
            const float ctab = (r == 0) ? cc0[k] : cc1[k];
            const float base = fmaf(COST_BBOX, l1, ctab);
            const float v = fmaf(-2.0f * num, rcpd, base);
            // coalesced NT dword store: lane i -> out[... + i + k*240]
            __builtin_nontemporal_store(v, obase + (size_t)r * NT + k * NJT);
        }
    }
}

// ----------------------------- generic fallback -----------------------------
constexpr int GROWS = 8;
__global__ __launch_bounds__(THREADS) void matcher_kernel_g(
    const float* __restrict__ logits, const float* __restrict__ boxes,
    const int* __restrict__ tids, const float* __restrict__ tboxes,
    float* __restrict__ out, int BN, int NC, int NT)
{
    extern __shared__ float s_cls_g[];
    const int tid  = threadIdx.x;
    const int row0 = blockIdx.x * GROWS;
    const int nrows = (BN - row0 < GROWS) ? (BN - row0) : GROWS;

    for (int t = tid; t < nrows * NC; t += THREADS) {
        const int r = t / NC, c = t - r * NC;
        const float x = logits[(size_t)(row0 + r) * NC + c];
        const float p  = 1.0f / (1.0f + expf(-x));
        const float om = 1.0f - p;
        const float neg = (1.0f - ALPHA_F) * p * p * (-logf(om + EPS_F));
        const float pos = ALPHA_F * om * om        * (-logf(p + EPS_F));
        s_cls_g[r * NC + c] = pos - neg;
    }
    __syncthreads();

    for (int r = 0; r < nrows; ++r) {
        const int row = row0 + r;
        const float4 pb = reinterpret_cast<const float4*>(boxes)[row];
        const float px0 = pb.x - 0.5f * pb.z, py0 = pb.y - 0.5f * pb.w;
        const float px1 = pb.x + 0.5f * pb.z, py1 = pb.y + 0.5f * pb.w;
        const float parea = pb.z * pb.w;
        for (int j = tid; j < NT; j += THREADS) {
            const float4 b = reinterpret_cast<const float4*>(tboxes)[j];
            const float bx0 = b.x - 0.5f * b.z, by0 = b.y - 0.5f * b.w;
            const float bx1 = b.x + 0.5f * b.z, by1 = b.y + 0.5f * b.w;
            const float l1 = fabsf(pb.x - b.x) + fabsf(pb.y - b.y)
                           + fabsf(pb.z - b.z) + fabsf(pb.w - b.w);
            const float iw = fmaxf(fminf(px1, bx1) - fmaxf(px0, bx0), 0.0f);
            const float ih = fmaxf(fminf(py1, by1) - fmaxf(py0, by0), 0.0f);
            const float inter = iw * ih;
            const float uni = parea + b.z * b.w - inter;
            const float iou = inter / uni;
            const float cw = fmaxf(px1, bx1) - fminf(px0, bx0);
            const float ch = fmaxf(py1, by1) - fminf(py0, by0);
            const float carea = cw * ch;
            const float giou = iou - (carea - uni) / carea;
            const float ccls = s_cls_g[r * NC + tids[j]];
            out[(size_t)row * NT + j] = COST_BBOX * l1 + COST_CLS * ccls - COST_GIOU * giou;
        }
        __syncthreads();
    }
}

extern "C" void kernel_launch(void* const* d_in, const int* in_sizes, int n_in,
                              void* d_out, int out_size, void* d_ws, size_t ws_size,
                              hipStream_t stream) {
    const float* logits = (const float*)d_in[0];
    const float* boxes  = (const float*)d_in[1];
    const int*   tids   = (const int*)d_in[2];
    const float* tboxes = (const float*)d_in[3];
    float* out = (float*)d_out;

    const int BN = in_sizes[1] / 4;       // 14400
    const int NC = in_sizes[0] / BN;      // 91
    const int NT = in_sizes[2];           // 960

    if (NC == 91 && NT == 960 && BN % 2 == 0) {
        matcher_kernel_s<91, 960><<<BN / 2, THREADS, 0, stream>>>(
            logits, boxes, tids, tboxes, out);
    } else {
        const int grid = (BN + GROWS - 1) / GROWS;
        const size_t shmem = (size_t)GROWS * NC * sizeof(float);
        matcher_kernel_g<<<grid, THREADS, shmem, stream>>>(
            logits, boxes, tids, tboxes, out, BN, NC, NT);
    }
}